// Round 16
// baseline (2330.588 us; speedup 1.0000x reference)
//
#include <hip/hip_runtime.h>
#include <cstdint>
#include <cstddef>

// Problem constants (Swin window attention)
#define B_WIN   2048
#define N_TOK   64
#define C_DIM   512
#define H_HEADS 16
#define D_HEAD  32
#define K_DIM   512
#define M_ROWS  (B_WIN * 64)   // 131072

// Tiled operand layout for GEMM operands (bf16), 128-row granules:
//   T[mb][kt][s][r][e]  mb=row>>7, kt=k>>5, s=(k>>3)&3, r=row&127, e=k&7
//   flat elem = mb*65536 + kt*4096 + s*1024 + r*8 + e

typedef __bf16 bf16x8 __attribute__((ext_vector_type(8)));
typedef float  f32x4  __attribute__((ext_vector_type(4)));
typedef unsigned short u16x8 __attribute__((ext_vector_type(8)));

__device__ __forceinline__ unsigned short f2bf_rn(float f) {
    unsigned u = __float_as_uint(f);
    u += 0x7fffu + ((u >> 16) & 1u);
    return (unsigned short)(u >> 16);
}
__device__ __forceinline__ float bf2f(unsigned short h) {
    return __uint_as_float(((unsigned)h) << 16);
}
__device__ __forceinline__ void gload16(const void* g, void* l) {
    __builtin_amdgcn_global_load_lds(
        (const __attribute__((address_space(1))) void*)g,
        (__attribute__((address_space(3))) void*)l,
        16, 0, 0);
}

// ---------------------------------------------------------------------------
// prep: fused {xsplit | qkv wsplit | bias_expand} (grid-partitioned).
// ---------------------------------------------------------------------------
__global__ __launch_bounds__(256) void prep_kernel(
    const float* __restrict__ x,
    unsigned short* __restrict__ Xh,
    unsigned short* __restrict__ Xl,
    const float* __restrict__ qkv_w,
    unsigned short* __restrict__ qwTh,
    unsigned short* __restrict__ qwTl,
    const float* __restrict__ bias_table,
    const int* __restrict__ rel_index,
    float* __restrict__ bias_hn)
{
    const int blk = blockIdx.x;
    if (blk < 32768) {
        size_t e8 = ((size_t)blk * 256 + threadIdx.x) * 8;
        const int mb = (int)(e8 >> 16);
        const int w  = (int)(e8 & 65535);
        const int kt = w >> 12;
        const int s  = (w >> 10) & 3;
        const int r  = (w >> 3) & 127;
        const int m  = mb * 128 + r;
        const int k  = kt * 32 + s * 8;
        const float* src = &x[(size_t)m * 512 + k];
        float4 f0 = *reinterpret_cast<const float4*>(src);
        float4 f1 = *reinterpret_cast<const float4*>(src + 4);
        float fv[8] = {f0.x, f0.y, f0.z, f0.w, f1.x, f1.y, f1.z, f1.w};
        u16x8 hi, lo;
#pragma unroll
        for (int j = 0; j < 8; ++j) {
            unsigned short h = f2bf_rn(fv[j]);
            hi[j] = h;
            lo[j] = f2bf_rn(fv[j] - bf2f(h));
        }
        *reinterpret_cast<u16x8*>(&Xh[e8]) = hi;
        *reinterpret_cast<u16x8*>(&Xl[e8]) = lo;
    } else if (blk < 33152) {
        size_t e8 = ((size_t)(blk - 32768) * 256 + threadIdx.x) * 8;
        const int mb = (int)(e8 >> 16);
        const int ww = (int)(e8 & 65535);
        const int kt = ww >> 12;
        const int s  = (ww >> 10) & 3;
        const int r  = (ww >> 3) & 127;
        const int n  = mb * 128 + r;
        const int k  = kt * 32 + s * 8;
        u16x8 hi, lo;
#pragma unroll
        for (int j = 0; j < 8; ++j) {
            float v = qkv_w[(size_t)(k + j) * 1536 + n];
            unsigned short h = f2bf_rn(v);
            hi[j] = h;
            lo[j] = f2bf_rn(v - bf2f(h));
        }
        *reinterpret_cast<u16x8*>(&qwTh[e8]) = hi;
        *reinterpret_cast<u16x8*>(&qwTl[e8]) = lo;
    } else {
        int tid = (blk - 33152) * 256 + threadIdx.x;
        int h  = tid >> 12;
        int ij = tid & 4095;
        bias_hn[tid] = bias_table[rel_index[ij] * H_HEADS + h];
    }
}

// ---------------------------------------------------------------------------
// wsplit (proj_w only; runs after attn because of its parking region)
// ---------------------------------------------------------------------------
__global__ __launch_bounds__(256) void wsplit_kernel(
    const float* __restrict__ w,
    unsigned short* __restrict__ wTh,
    unsigned short* __restrict__ wTl,
    int Ncols)
{
    size_t e8 = ((size_t)blockIdx.x * 256 + threadIdx.x) * 8;
    const int mb = (int)(e8 >> 16);
    const int ww = (int)(e8 & 65535);
    const int kt = ww >> 12;
    const int s  = (ww >> 10) & 3;
    const int r  = (ww >> 3) & 127;
    const int n  = mb * 128 + r;
    const int k  = kt * 32 + s * 8;
    u16x8 hi, lo;
#pragma unroll
    for (int j = 0; j < 8; ++j) {
        float v = w[(size_t)(k + j) * Ncols + n];
        unsigned short h = f2bf_rn(v);
        hi[j] = h;
        lo[j] = f2bf_rn(v - bf2f(h));
    }
    *reinterpret_cast<u16x8*>(&wTh[e8]) = hi;
    *reinterpret_cast<u16x8*>(&wTl[e8]) = lo;
}

// ---------------------------------------------------------------------------
// bf16-split MFMA GEMM, 256x256 tile, BK=32, 16 steps, 8 waves.
// R13-proven 2-buffer skeleton. Template MODE:
//   MODE=0 (QKV): A = Xh/Xl, B = qkv_w hi/lo. Column-block-uniform tsel:
//     q/k blocks (tsel<2): 2 passes (ah*bh + ah*bl), NO Al stage.
//     v blocks   (tsel=2): 3 passes (+ al*bh), v written hi/lo.
//     Epilogue: pair-packed u32 bf16 stores (shfl_xor lane merge).
//   MODE=1 (proj): A = avh (exact bf16), 2 passes; epilogue fp32 + bias.
// ---------------------------------------------------------------------------
template<int MODE>
__global__ __launch_bounds__(512, 2) void gemm_mfma_kernel(
    const unsigned short* __restrict__ ATh,
    const unsigned short* __restrict__ ATl,   // null when MODE==1
    const unsigned short* __restrict__ BTh,
    const unsigned short* __restrict__ BTl,
    unsigned short* __restrict__ qh,          // MODE==0 outputs
    unsigned short* __restrict__ kh,
    unsigned short* __restrict__ vh,
    unsigned short* __restrict__ vl,
    const float* __restrict__ bias,           // MODE==1
    float* __restrict__ out,                  // MODE==1
    int Ncols_out,
    int nb_grid)                              // blocks along n (Ncols/256)
{
    extern __shared__ __align__(16) unsigned short L[];
    constexpr int AH = 0;
    constexpr int AL = 8192;                              // MODE==0 v-blocks
    constexpr int BH = (MODE == 0) ? 16384 : 8192;
    constexpr int BL = (MODE == 0) ? 24576 : 16384;
    constexpr int STRIDE = (MODE == 0) ? 32768 : 24576;

    const int t    = threadIdx.x;
    const int lane = t & 63;
    const int wave = t >> 6;             // 0..7
    const int lg   = lane >> 4;          // k-octet 0..3
    const int lr   = lane & 15;          // row within fragment
    const int wrow = (wave >> 2) * 128;  // 0,128
    const int wcol = (wave & 3) * 64;    // 0,64,128,192

    const int lin = blockIdx.x + gridDim.x * blockIdx.y;
    const int nwg = gridDim.x * gridDim.y;
    const int cpx = nwg >> 3;
    const int swz = (lin & 7) * cpx + (lin >> 3);
    const int m0  = (swz / nb_grid) * 256;
    const int n0  = (swz % nb_grid) * 256;
    const int mb0 = m0 >> 7;
    const int nb0 = n0 >> 7;
    const int tsel = n0 >> 9;                  // block-uniform (MODE 0)
    const bool lo3 = (MODE == 0) && (tsel == 2);

    f32x4 acc[8][4];
#pragma unroll
    for (int i = 0; i < 8; ++i)
#pragma unroll
        for (int j = 0; j < 4; ++j) acc[i][j] = (f32x4){0.f, 0.f, 0.f, 0.f};

    auto stage = [&](int kt, int bi) {
        const int bufbase = bi * STRIDE;
#pragma unroll
        for (int i = 0; i < 2; ++i) {
            const int c = i * 512 + t;        // 0..1023
            const int r = c & 255;
            const int s = c >> 8;
            const size_t gA = (size_t)(mb0 + (r >> 7)) * 65536
                            + (size_t)kt * 4096 + s * 1024 + (r & 127) * 8;
            const size_t gB = (size_t)(nb0 + (r >> 7)) * 65536
                            + (size_t)kt * 4096 + s * 1024 + (r & 127) * 8;
            const int lo = bufbase + s * 2048 + r * 8;
            gload16(&ATh[gA], &L[lo + AH]);
            if (MODE == 0 && lo3) gload16(&ATl[gA], &L[lo + AL]);
            gload16(&BTh[gB], &L[lo + BH]);
            gload16(&BTl[gB], &L[lo + BL]);
        }
    };

    stage(0, 0);
    asm volatile("s_waitcnt vmcnt(0)" ::: "memory");
    __builtin_amdgcn_sched_barrier(0);
    __builtin_amdgcn_s_barrier();
    __builtin_amdgcn_sched_barrier(0);

#pragma unroll 2
    for (int ks = 0; ks < 16; ++ks) {
        const int cur = ks & 1;
        if (ks + 1 < 16) stage(ks + 1, cur ^ 1);
        const int bb = cur * STRIDE;

        bf16x8 bh[4], bl[4];
#pragma unroll
        for (int ni = 0; ni < 4; ++ni) {
            const int off = bb + lg * 2048 + (wcol + ni * 16 + lr) * 8;
            bh[ni] = *reinterpret_cast<const bf16x8*>(&L[off + BH]);
            bl[ni] = *reinterpret_cast<const bf16x8*>(&L[off + BL]);
        }
        __builtin_amdgcn_s_setprio(1);
        if (lo3) {
#pragma unroll
            for (int mi = 0; mi < 8; ++mi) {
                const int aoff = bb + lg * 2048 + (wrow + mi * 16 + lr) * 8;
                bf16x8 ah = *reinterpret_cast<const bf16x8*>(&L[aoff + AH]);
                bf16x8 al = *reinterpret_cast<const bf16x8*>(&L[aoff + AL]);
#pragma unroll
                for (int ni = 0; ni < 4; ++ni)
                    acc[mi][ni] = __builtin_amdgcn_mfma_f32_16x16x32_bf16(ah, bh[ni], acc[mi][ni], 0, 0, 0);
#pragma unroll
                for (int ni = 0; ni < 4; ++ni)
                    acc[mi][ni] = __builtin_amdgcn_mfma_f32_16x16x32_bf16(ah, bl[ni], acc[mi][ni], 0, 0, 0);
#pragma unroll
                for (int ni = 0; ni < 4; ++ni)
                    acc[mi][ni] = __builtin_amdgcn_mfma_f32_16x16x32_bf16(al, bh[ni], acc[mi][ni], 0, 0, 0);
            }
        } else {
#pragma unroll
            for (int mi = 0; mi < 8; ++mi) {
                const int aoff = bb + lg * 2048 + (wrow + mi * 16 + lr) * 8;
                bf16x8 ah = *reinterpret_cast<const bf16x8*>(&L[aoff + AH]);
#pragma unroll
                for (int ni = 0; ni < 4; ++ni)
                    acc[mi][ni] = __builtin_amdgcn_mfma_f32_16x16x32_bf16(ah, bh[ni], acc[mi][ni], 0, 0, 0);
#pragma unroll
                for (int ni = 0; ni < 4; ++ni)
                    acc[mi][ni] = __builtin_amdgcn_mfma_f32_16x16x32_bf16(ah, bl[ni], acc[mi][ni], 0, 0, 0);
            }
        }
        __builtin_amdgcn_s_setprio(0);

        asm volatile("s_waitcnt vmcnt(0)" ::: "memory");
        __builtin_amdgcn_sched_barrier(0);
        __builtin_amdgcn_s_barrier();
        __builtin_amdgcn_sched_barrier(0);
    }

    // C/D layout: col = lane&15, row = (lane>>4)*4 + reg   [m89-verified]
    if constexpr (MODE == 0) {
        unsigned short* dh = (tsel == 0) ? qh : (tsel == 1) ? kh : vh;
#pragma unroll
        for (int mi = 0; mi < 8; ++mi)
#pragma unroll
            for (int ni = 0; ni < 4; ++ni) {
                const int col = n0 + wcol + ni * 16 + lr;
                const int h   = (col >> 5) & 15;
                const int dd  = col & 31;
#pragma unroll
                for (int reg = 0; reg < 4; ++reg) {
                    const int row = m0 + wrow + mi * 16 + lg * 4 + reg;
                    const int b = row >> 6, n = row & 63;
                    const size_t idx = ((((size_t)b * H_HEADS + h) * 64) + n) * 32 + dd;
                    const float own  = acc[mi][ni][reg];
                    const float mate = __shfl_xor(own, 1);
                    if (!(lr & 1)) {
                        unsigned short h0 = f2bf_rn(own);
                        unsigned short h1 = f2bf_rn(mate);
                        *reinterpret_cast<unsigned*>(&dh[idx]) =
                            (unsigned)h0 | ((unsigned)h1 << 16);
                        if (tsel == 2) {
                            unsigned short l0 = f2bf_rn(own  - bf2f(h0));
                            unsigned short l1 = f2bf_rn(mate - bf2f(h1));
                            *reinterpret_cast<unsigned*>(&vl[idx]) =
                                (unsigned)l0 | ((unsigned)l1 << 16);
                        }
                    }
                }
            }
    } else {
#pragma unroll
        for (int mi = 0; mi < 8; ++mi)
#pragma unroll
            for (int ni = 0; ni < 4; ++ni) {
                const int col = n0 + wcol + ni * 16 + lr;
                const float pb = bias[col];
#pragma unroll
                for (int reg = 0; reg < 4; ++reg) {
                    const int row = m0 + wrow + mi * 16 + lg * 4 + reg;
                    out[(size_t)row * Ncols_out + col] = acc[mi][ni][reg] + pb;
                }
            }
    }
}

// ---------------------------------------------------------------------------
// MFMA window attention (unchanged from R15 — proven). q,k bf16 (1-pass
// QK^T); v hi/lo (3-pass PV); av emitted bf16-hi (tiled).
// ---------------------------------------------------------------------------
__global__ __launch_bounds__(256, 4) void attn_kernel(
    const unsigned short* __restrict__ qh,   // [B][H][64][32] bf16
    const unsigned short* __restrict__ kh,
    const unsigned short* __restrict__ vh,
    const unsigned short* __restrict__ vl,
    const float* __restrict__ bias_hn,       // [H][64][64]
    float* __restrict__ attn_map,            // [B][H][64][64]
    unsigned short* __restrict__ avh)        // tiled bf16 hi
{
    __shared__ __align__(16) unsigned short SM[18944];
    constexpr int VTH = 0, VTL = 2304;       // [32 d][72 r]
    constexpr int QS  = 4608, KS = 7168;     // [64][40]
    constexpr int PH  = 9728, PL = 14336;    // [64][72]

    const int bhid = blockIdx.x;
    const int b    = bhid >> 4;
    const int h    = bhid & 15;
    const int t    = threadIdx.x;
    const int lane = t & 63;
    const int wv   = t >> 6;
    const int lg   = lane >> 4;
    const int lr   = lane & 15;

    const size_t base = (size_t)bhid * 2048;   // 64*32 per (b,h)

    {
        const int r  = t >> 2;
        const int c0 = (t & 3) * 8;
        u16x8 q8 = *reinterpret_cast<const u16x8*>(&qh[base + r * 32 + c0]);
        *reinterpret_cast<u16x8*>(&SM[QS + r * 40 + c0]) = q8;
        u16x8 k8 = *reinterpret_cast<const u16x8*>(&kh[base + r * 32 + c0]);
        *reinterpret_cast<u16x8*>(&SM[KS + r * 40 + c0]) = k8;
        u16x8 vh8 = *reinterpret_cast<const u16x8*>(&vh[base + r * 32 + c0]);
        u16x8 vl8 = *reinterpret_cast<const u16x8*>(&vl[base + r * 32 + c0]);
#pragma unroll
        for (int u = 0; u < 8; ++u) {
            const int d = c0 + u;
            SM[VTH + d * 72 + r] = vh8[u];
            SM[VTL + d * 72 + r] = vl8[u];
        }
    }
    __syncthreads();

    float bias[4][4];
#pragma unroll
    for (int reg = 0; reg < 4; ++reg)
#pragma unroll
        for (int c = 0; c < 4; ++c)
            bias[reg][c] = bias_hn[(h << 12) + ((wv * 16 + lg * 4 + reg) << 6) + c * 16 + lr];

    const int ar = wv * 16 + lr;
    bf16x8 qa = *reinterpret_cast<const bf16x8*>(&SM[QS + ar * 40 + lg * 8]);
    f32x4 S[4];
#pragma unroll
    for (int c = 0; c < 4; ++c) {
        const int br = c * 16 + lr;
        bf16x8 kb = *reinterpret_cast<const bf16x8*>(&SM[KS + br * 40 + lg * 8]);
        f32x4 s = (f32x4){0.f, 0.f, 0.f, 0.f};
        S[c] = __builtin_amdgcn_mfma_f32_16x16x32_bf16(qa, kb, s, 0, 0, 0);
    }
    // no barrier: P region is disjoint from QS/KS/VT

    const float scale = 0.1767766952966369f;  // 32^-0.5
    float p[4][4], mx[4], sm[4];
#pragma unroll
    for (int reg = 0; reg < 4; ++reg) mx[reg] = -1e30f;
#pragma unroll
    for (int reg = 0; reg < 4; ++reg)
#pragma unroll
        for (int c = 0; c < 4; ++c) {
            float s = fmaf(S[c][reg], scale, bias[reg][c]);
            p[reg][c] = s;
            mx[reg] = fmaxf(mx[reg], s);
        }
#pragma unroll
    for (int reg = 0; reg < 4; ++reg) {
        mx[reg] = fmaxf(mx[reg], __shfl_xor(mx[reg], 1));
        mx[reg] = fmaxf(mx[reg], __shfl_xor(mx[reg], 2));
        mx[reg] = fmaxf(mx[reg], __shfl_xor(mx[reg], 4));
        mx[reg] = fmaxf(mx[reg], __shfl_xor(mx[reg], 8));
        sm[reg] = 0.f;
    }
#pragma unroll
    for (int reg = 0; reg < 4; ++reg)
#pragma unroll
        for (int c = 0; c < 4; ++c) {
            float e = __expf(p[reg][c] - mx[reg]);
            p[reg][c] = e;
            sm[reg] += e;
        }
#pragma unroll
    for (int reg = 0; reg < 4; ++reg) {
        sm[reg] += __shfl_xor(sm[reg], 1);
        sm[reg] += __shfl_xor(sm[reg], 2);
        sm[reg] += __shfl_xor(sm[reg], 4);
        sm[reg] += __shfl_xor(sm[reg], 8);
        const float inv = 1.0f / sm[reg];
#pragma unroll
        for (int c = 0; c < 4; ++c) p[reg][c] *= inv;
    }

    const size_t amb = (size_t)bhid * 4096;
#pragma unroll
    for (int reg = 0; reg < 4; ++reg) {
        const int R = wv * 16 + lg * 4 + reg;
#pragma unroll
        for (int c = 0; c < 4; ++c) {
            const int C = c * 16 + lr;
            const float own = p[reg][c];
            attn_map[amb + R * 64 + C] = own;
            const float mate = __shfl_xor(own, 1);
            if (!(lr & 1)) {
                unsigned short h0 = f2bf_rn(own);
                unsigned short l0 = f2bf_rn(own - bf2f(h0));
                unsigned short h1 = f2bf_rn(mate);
                unsigned short l1 = f2bf_rn(mate - bf2f(h1));
                *reinterpret_cast<unsigned*>(&SM[PH + R * 72 + C]) =
                    (unsigned)h0 | ((unsigned)h1 << 16);
                *reinterpret_cast<unsigned*>(&SM[PL + R * 72 + C]) =
                    (unsigned)l0 | ((unsigned)l1 << 16);
            }
        }
    }
    // no barrier: wave wv's PV a-frags read rows 16wv..16wv+15 = its own writes

    f32x4 O[2];
    O[0] = (f32x4){0.f, 0.f, 0.f, 0.f};
    O[1] = (f32x4){0.f, 0.f, 0.f, 0.f};
#pragma unroll
    for (int kk = 0; kk < 2; ++kk) {
        const int pr = wv * 16 + lr;
        bf16x8 pa_h = *reinterpret_cast<const bf16x8*>(&SM[PH + pr * 72 + kk * 32 + lg * 8]);
        bf16x8 pa_l = *reinterpret_cast<const bf16x8*>(&SM[PL + pr * 72 + kk * 32 + lg * 8]);
#pragma unroll
        for (int n = 0; n < 2; ++n) {
            const int vr = n * 16 + lr;
            bf16x8 vb_h = *reinterpret_cast<const bf16x8*>(&SM[VTH + vr * 72 + kk * 32 + lg * 8]);
            bf16x8 vb_l = *reinterpret_cast<const bf16x8*>(&SM[VTL + vr * 72 + kk * 32 + lg * 8]);
            O[n] = __builtin_amdgcn_mfma_f32_16x16x32_bf16(pa_h, vb_h, O[n], 0, 0, 0);
            O[n] = __builtin_amdgcn_mfma_f32_16x16x32_bf16(pa_h, vb_l, O[n], 0, 0, 0);
            O[n] = __builtin_amdgcn_mfma_f32_16x16x32_bf16(pa_l, vb_h, O[n], 0, 0, 0);
        }
    }

    // av store: tiled layout [mb][kt=h][s][r][e], bf16 hi only
    const int mb = b >> 1;
#pragma unroll
    for (int n = 0; n < 2; ++n)
#pragma unroll
        for (int reg = 0; reg < 4; ++reg) {
            const int R  = wv * 16 + lg * 4 + reg;
            const int d  = n * 16 + lr;
            const int rl = (b & 1) * 64 + R;
            size_t off = (size_t)mb * 65536 + (size_t)h * 4096
                       + (size_t)(d >> 3) * 1024 + (size_t)rl * 8 + (d & 7);
            avh[off] = f2bf_rn(O[n][reg]);
        }
}

// ---------------------------------------------------------------------------
extern "C" void kernel_launch(void* const* d_in, const int* in_sizes, int n_in,
                              void* d_out, int out_size, void* d_ws, size_t ws_size,
                              hipStream_t stream) {
    const float* x          = (const float*)d_in[0];
    const float* qkv_w      = (const float*)d_in[1];
    const float* proj_w     = (const float*)d_in[2];
    const float* proj_b     = (const float*)d_in[3];
    const float* bias_table = (const float*)d_in[4];
    const int*   rel_index  = (const int*)d_in[5];

    float* out      = (float*)d_out;                           // [131072][512]
    float* attn_map = (float*)d_out + (size_t)M_ROWS * C_DIM;  // [B][H][64][64]

    // d_ws: Xh | Xl (tiled bf16) | qh | kh | vh | vl (bf16 planes)
    // avh aliases Xh (dead after QKV GEMM).
    const size_t PLANE = (size_t)B_WIN * H_HEADS * 64 * 32;    // 67,108,864
    unsigned short* Xh  = (unsigned short*)d_ws;
    unsigned short* Xl  = Xh + (size_t)M_ROWS * 512;
    unsigned short* qhp = Xl + (size_t)M_ROWS * 512;
    unsigned short* khp = qhp + PLANE;
    unsigned short* vhp = khp + PLANE;
    unsigned short* vlp = vhp + PLANE;
    unsigned short* avh = Xh;

    // parking: qkv_w split -> attn_map region of d_out (dead until attn
    // overwrites it); proj_w split -> qh head (dead after attn reads qh);
    // bias_hn -> out head (read by attn, before proj writes out).
    unsigned short* qwTh = (unsigned short*)attn_map;
    unsigned short* qwTl = qwTh + (size_t)1536 * 512;
    unsigned short* pwTh = qhp;
    unsigned short* pwTl = pwTh + (size_t)512 * 512;
    float* bias_hn = out;

    prep_kernel<<<33408, 256, 0, stream>>>(
        x, Xh, Xl, qkv_w, qwTh, qwTl, bias_table, rel_index, bias_hn);
    gemm_mfma_kernel<0><<<dim3(6, 512), 512, 131072, stream>>>(
        Xh, Xl, qwTh, qwTl, qhp, khp, vhp, vlp, nullptr, nullptr, 1536, 6);
    attn_kernel<<<B_WIN * H_HEADS, 256, 0, stream>>>(
        qhp, khp, vhp, vlp, bias_hn, attn_map, avh);
    wsplit_kernel<<<128, 256, 0, stream>>>(proj_w, pwTh, pwTl, 512);
    gemm_mfma_kernel<1><<<dim3(2, 512), 512, 98304, stream>>>(
        avh, nullptr, pwTh, pwTl, nullptr, nullptr, nullptr, nullptr,
        proj_b, out, 512, 2);
}

// Round 17
// 1003.713 us; speedup vs baseline: 2.3220x; 2.3220x over previous
//
#include <hip/hip_runtime.h>
#include <cstdint>
#include <cstddef>

// Problem constants (Swin window attention)
#define B_WIN   2048
#define N_TOK   64
#define C_DIM   512
#define H_HEADS 16
#define D_HEAD  32
#define K_DIM   512
#define M_ROWS  (B_WIN * 64)   // 131072

// Tiled operand layout for GEMM operands (bf16), 128-row granules:
//   T[mb][kt][s][r][e]  mb=row>>7, kt=k>>5, s=(k>>3)&3, r=row&127, e=k&7
//   flat elem = mb*65536 + kt*4096 + s*1024 + r*8 + e

typedef __bf16 bf16x8 __attribute__((ext_vector_type(8)));
typedef float  f32x4  __attribute__((ext_vector_type(4)));
typedef unsigned short u16x8 __attribute__((ext_vector_type(8)));

__device__ __forceinline__ unsigned short f2bf_rn(float f) {
    unsigned u = __float_as_uint(f);
    u += 0x7fffu + ((u >> 16) & 1u);
    return (unsigned short)(u >> 16);
}
__device__ __forceinline__ float bf2f(unsigned short h) {
    return __uint_as_float(((unsigned)h) << 16);
}
__device__ __forceinline__ void gload16(const void* g, void* l) {
    __builtin_amdgcn_global_load_lds(
        (const __attribute__((address_space(1))) void*)g,
        (__attribute__((address_space(3))) void*)l,
        16, 0, 0);
}

// ---------------------------------------------------------------------------
// prep: fused {xsplit | qkv wsplit | bias_expand} (grid-partitioned).
// ---------------------------------------------------------------------------
__global__ __launch_bounds__(256) void prep_kernel(
    const float* __restrict__ x,
    unsigned short* __restrict__ Xh,
    unsigned short* __restrict__ Xl,
    const float* __restrict__ qkv_w,
    unsigned short* __restrict__ qwTh,
    unsigned short* __restrict__ qwTl,
    const float* __restrict__ bias_table,
    const int* __restrict__ rel_index,
    float* __restrict__ bias_hn)
{
    const int blk = blockIdx.x;
    if (blk < 32768) {
        size_t e8 = ((size_t)blk * 256 + threadIdx.x) * 8;
        const int mb = (int)(e8 >> 16);
        const int w  = (int)(e8 & 65535);
        const int kt = w >> 12;
        const int s  = (w >> 10) & 3;
        const int r  = (w >> 3) & 127;
        const int m  = mb * 128 + r;
        const int k  = kt * 32 + s * 8;
        const float* src = &x[(size_t)m * 512 + k];
        float4 f0 = *reinterpret_cast<const float4*>(src);
        float4 f1 = *reinterpret_cast<const float4*>(src + 4);
        float fv[8] = {f0.x, f0.y, f0.z, f0.w, f1.x, f1.y, f1.z, f1.w};
        u16x8 hi, lo;
#pragma unroll
        for (int j = 0; j < 8; ++j) {
            unsigned short h = f2bf_rn(fv[j]);
            hi[j] = h;
            lo[j] = f2bf_rn(fv[j] - bf2f(h));
        }
        *reinterpret_cast<u16x8*>(&Xh[e8]) = hi;
        *reinterpret_cast<u16x8*>(&Xl[e8]) = lo;
    } else if (blk < 33152) {
        size_t e8 = ((size_t)(blk - 32768) * 256 + threadIdx.x) * 8;
        const int mb = (int)(e8 >> 16);
        const int ww = (int)(e8 & 65535);
        const int kt = ww >> 12;
        const int s  = (ww >> 10) & 3;
        const int r  = (ww >> 3) & 127;
        const int n  = mb * 128 + r;
        const int k  = kt * 32 + s * 8;
        u16x8 hi, lo;
#pragma unroll
        for (int j = 0; j < 8; ++j) {
            float v = qkv_w[(size_t)(k + j) * 1536 + n];
            unsigned short h = f2bf_rn(v);
            hi[j] = h;
            lo[j] = f2bf_rn(v - bf2f(h));
        }
        *reinterpret_cast<u16x8*>(&qwTh[e8]) = hi;
        *reinterpret_cast<u16x8*>(&qwTl[e8]) = lo;
    } else {
        int tid = (blk - 33152) * 256 + threadIdx.x;
        int h  = tid >> 12;
        int ij = tid & 4095;
        bias_hn[tid] = bias_table[rel_index[ij] * H_HEADS + h];
    }
}

// ---------------------------------------------------------------------------
// wsplit (proj_w only; runs after attn because of its parking region)
// ---------------------------------------------------------------------------
__global__ __launch_bounds__(256) void wsplit_kernel(
    const float* __restrict__ w,
    unsigned short* __restrict__ wTh,
    unsigned short* __restrict__ wTl,
    int Ncols)
{
    size_t e8 = ((size_t)blockIdx.x * 256 + threadIdx.x) * 8;
    const int mb = (int)(e8 >> 16);
    const int ww = (int)(e8 & 65535);
    const int kt = ww >> 12;
    const int s  = (ww >> 10) & 3;
    const int r  = (ww >> 3) & 127;
    const int n  = mb * 128 + r;
    const int k  = kt * 32 + s * 8;
    u16x8 hi, lo;
#pragma unroll
    for (int j = 0; j < 8; ++j) {
        float v = w[(size_t)(k + j) * Ncols + n];
        unsigned short h = f2bf_rn(v);
        hi[j] = h;
        lo[j] = f2bf_rn(v - bf2f(h));
    }
    *reinterpret_cast<u16x8*>(&wTh[e8]) = hi;
    *reinterpret_cast<u16x8*>(&wTl[e8]) = lo;
}

// ---------------------------------------------------------------------------
// bf16-split MFMA GEMM, 256x256 tile, BK=32, 16 steps, 8 waves.
// R13-proven 2-buffer skeleton. COMPILE-TIME MODE (R16's runtime branch
// caused scratch spill -> 6.3GB traffic; this restores constexpr loops):
//   MODE=0 (q/k): 2 passes (ah*bh + ah*bl); stages Ah,Bh,Bl; pair-packed
//                 bf16 out to qh or kh (tsel in {0,1}).
//   MODE=1 (v):   3 passes (+ al*bh); stages Ah,Al,Bh,Bl; vh+vl out.
//   MODE=2 (proj): 2 passes; A = avh exact bf16; fp32+bias out.
// ---------------------------------------------------------------------------
template<int MODE>
__global__ __launch_bounds__(512, 2) void gemm_mfma_kernel(
    const unsigned short* __restrict__ ATh,
    const unsigned short* __restrict__ ATl,   // MODE==1 only
    const unsigned short* __restrict__ BTh,
    const unsigned short* __restrict__ BTl,
    unsigned short* __restrict__ qh,          // MODE==0
    unsigned short* __restrict__ kh,          // MODE==0
    unsigned short* __restrict__ vh,          // MODE==1
    unsigned short* __restrict__ vl,          // MODE==1
    const float* __restrict__ bias,           // MODE==2
    float* __restrict__ out,                  // MODE==2
    int Ncols_out,
    int nb_grid,                              // blocks along n
    int n_base)                               // column offset of this launch
{
    extern __shared__ __align__(16) unsigned short L[];
    constexpr bool THREE = (MODE == 1);
    constexpr int AH = 0;
    constexpr int AL = 8192;                        // THREE only
    constexpr int BH = THREE ? 16384 : 8192;
    constexpr int BL = THREE ? 24576 : 16384;
    constexpr int STRIDE = THREE ? 32768 : 24576;

    const int t    = threadIdx.x;
    const int lane = t & 63;
    const int wave = t >> 6;             // 0..7
    const int lg   = lane >> 4;          // k-octet 0..3
    const int lr   = lane & 15;          // row within fragment
    const int wrow = (wave >> 2) * 128;  // 0,128
    const int wcol = (wave & 3) * 64;    // 0,64,128,192

    const int lin = blockIdx.x + gridDim.x * blockIdx.y;
    const int nwg = gridDim.x * gridDim.y;
    const int cpx = nwg >> 3;
    const int swz = (lin & 7) * cpx + (lin >> 3);
    const int m0  = (swz / nb_grid) * 256;
    const int n0  = n_base + (swz % nb_grid) * 256;
    const int mb0 = m0 >> 7;
    const int nb0 = n0 >> 7;
    const int tsel = n0 >> 9;            // block-uniform

    f32x4 acc[8][4];
#pragma unroll
    for (int i = 0; i < 8; ++i)
#pragma unroll
        for (int j = 0; j < 4; ++j) acc[i][j] = (f32x4){0.f, 0.f, 0.f, 0.f};

    auto stage = [&](int kt, int bi) {
        const int bufbase = bi * STRIDE;
#pragma unroll
        for (int i = 0; i < 2; ++i) {
            const int c = i * 512 + t;        // 0..1023
            const int r = c & 255;
            const int s = c >> 8;
            const size_t gA = (size_t)(mb0 + (r >> 7)) * 65536
                            + (size_t)kt * 4096 + s * 1024 + (r & 127) * 8;
            const size_t gB = (size_t)(nb0 + (r >> 7)) * 65536
                            + (size_t)kt * 4096 + s * 1024 + (r & 127) * 8;
            const int lo = bufbase + s * 2048 + r * 8;
            gload16(&ATh[gA], &L[lo + AH]);
            if constexpr (THREE) gload16(&ATl[gA], &L[lo + AL]);
            gload16(&BTh[gB], &L[lo + BH]);
            gload16(&BTl[gB], &L[lo + BL]);
        }
    };

    stage(0, 0);
    asm volatile("s_waitcnt vmcnt(0)" ::: "memory");
    __builtin_amdgcn_sched_barrier(0);
    __builtin_amdgcn_s_barrier();
    __builtin_amdgcn_sched_barrier(0);

#pragma unroll 2
    for (int ks = 0; ks < 16; ++ks) {
        const int cur = ks & 1;
        if (ks + 1 < 16) stage(ks + 1, cur ^ 1);
        const int bb = cur * STRIDE;

        bf16x8 bh[4], bl[4];
#pragma unroll
        for (int ni = 0; ni < 4; ++ni) {
            const int off = bb + lg * 2048 + (wcol + ni * 16 + lr) * 8;
            bh[ni] = *reinterpret_cast<const bf16x8*>(&L[off + BH]);
            bl[ni] = *reinterpret_cast<const bf16x8*>(&L[off + BL]);
        }
        __builtin_amdgcn_s_setprio(1);
#pragma unroll
        for (int mi = 0; mi < 8; ++mi) {
            const int aoff = bb + lg * 2048 + (wrow + mi * 16 + lr) * 8;
            bf16x8 ah = *reinterpret_cast<const bf16x8*>(&L[aoff + AH]);
#pragma unroll
            for (int ni = 0; ni < 4; ++ni)
                acc[mi][ni] = __builtin_amdgcn_mfma_f32_16x16x32_bf16(ah, bh[ni], acc[mi][ni], 0, 0, 0);
#pragma unroll
            for (int ni = 0; ni < 4; ++ni)
                acc[mi][ni] = __builtin_amdgcn_mfma_f32_16x16x32_bf16(ah, bl[ni], acc[mi][ni], 0, 0, 0);
            if constexpr (THREE) {
                bf16x8 al = *reinterpret_cast<const bf16x8*>(&L[aoff + AL]);
#pragma unroll
                for (int ni = 0; ni < 4; ++ni)
                    acc[mi][ni] = __builtin_amdgcn_mfma_f32_16x16x32_bf16(al, bh[ni], acc[mi][ni], 0, 0, 0);
            }
        }
        __builtin_amdgcn_s_setprio(0);

        asm volatile("s_waitcnt vmcnt(0)" ::: "memory");
        __builtin_amdgcn_sched_barrier(0);
        __builtin_amdgcn_s_barrier();
        __builtin_amdgcn_sched_barrier(0);
    }

    // C/D layout: col = lane&15, row = (lane>>4)*4 + reg   [m89-verified]
    if constexpr (MODE == 0) {
        unsigned short* dh = (tsel == 1) ? kh : qh;
#pragma unroll
        for (int mi = 0; mi < 8; ++mi)
#pragma unroll
            for (int ni = 0; ni < 4; ++ni) {
                const int col = n0 + wcol + ni * 16 + lr;
                const int h   = (col >> 5) & 15;
                const int dd  = col & 31;
#pragma unroll
                for (int reg = 0; reg < 4; ++reg) {
                    const int row = m0 + wrow + mi * 16 + lg * 4 + reg;
                    const int b = row >> 6, n = row & 63;
                    const size_t idx = ((((size_t)b * H_HEADS + h) * 64) + n) * 32 + dd;
                    const float own  = acc[mi][ni][reg];
                    const float mate = __shfl_xor(own, 1);
                    if (!(lr & 1)) {
                        unsigned short h0 = f2bf_rn(own);
                        unsigned short h1 = f2bf_rn(mate);
                        *reinterpret_cast<unsigned*>(&dh[idx]) =
                            (unsigned)h0 | ((unsigned)h1 << 16);
                    }
                }
            }
    } else if constexpr (MODE == 1) {
#pragma unroll
        for (int mi = 0; mi < 8; ++mi)
#pragma unroll
            for (int ni = 0; ni < 4; ++ni) {
                const int col = n0 + wcol + ni * 16 + lr;
                const int h   = (col >> 5) & 15;
                const int dd  = col & 31;
#pragma unroll
                for (int reg = 0; reg < 4; ++reg) {
                    const int row = m0 + wrow + mi * 16 + lg * 4 + reg;
                    const int b = row >> 6, n = row & 63;
                    const size_t idx = ((((size_t)b * H_HEADS + h) * 64) + n) * 32 + dd;
                    const float own  = acc[mi][ni][reg];
                    const float mate = __shfl_xor(own, 1);
                    if (!(lr & 1)) {
                        unsigned short h0 = f2bf_rn(own);
                        unsigned short h1 = f2bf_rn(mate);
                        *reinterpret_cast<unsigned*>(&vh[idx]) =
                            (unsigned)h0 | ((unsigned)h1 << 16);
                        unsigned short l0 = f2bf_rn(own  - bf2f(h0));
                        unsigned short l1 = f2bf_rn(mate - bf2f(h1));
                        *reinterpret_cast<unsigned*>(&vl[idx]) =
                            (unsigned)l0 | ((unsigned)l1 << 16);
                    }
                }
            }
    } else {
#pragma unroll
        for (int mi = 0; mi < 8; ++mi)
#pragma unroll
            for (int ni = 0; ni < 4; ++ni) {
                const int col = n0 + wcol + ni * 16 + lr;
                const float pb = bias[col];
#pragma unroll
                for (int reg = 0; reg < 4; ++reg) {
                    const int row = m0 + wrow + mi * 16 + lg * 4 + reg;
                    out[(size_t)row * Ncols_out + col] = acc[mi][ni][reg] + pb;
                }
            }
    }
}

// ---------------------------------------------------------------------------
// MFMA window attention (unchanged from R15 — proven). q,k bf16 (1-pass
// QK^T); v hi/lo (3-pass PV); av emitted bf16-hi (tiled).
// ---------------------------------------------------------------------------
__global__ __launch_bounds__(256, 4) void attn_kernel(
    const unsigned short* __restrict__ qh,   // [B][H][64][32] bf16
    const unsigned short* __restrict__ kh,
    const unsigned short* __restrict__ vh,
    const unsigned short* __restrict__ vl,
    const float* __restrict__ bias_hn,       // [H][64][64]
    float* __restrict__ attn_map,            // [B][H][64][64]
    unsigned short* __restrict__ avh)        // tiled bf16 hi
{
    __shared__ __align__(16) unsigned short SM[18944];
    constexpr int VTH = 0, VTL = 2304;       // [32 d][72 r]
    constexpr int QS  = 4608, KS = 7168;     // [64][40]
    constexpr int PH  = 9728, PL = 14336;    // [64][72]

    const int bhid = blockIdx.x;
    const int b    = bhid >> 4;
    const int h    = bhid & 15;
    const int t    = threadIdx.x;
    const int lane = t & 63;
    const int wv   = t >> 6;
    const int lg   = lane >> 4;
    const int lr   = lane & 15;

    const size_t base = (size_t)bhid * 2048;   // 64*32 per (b,h)

    {
        const int r  = t >> 2;
        const int c0 = (t & 3) * 8;
        u16x8 q8 = *reinterpret_cast<const u16x8*>(&qh[base + r * 32 + c0]);
        *reinterpret_cast<u16x8*>(&SM[QS + r * 40 + c0]) = q8;
        u16x8 k8 = *reinterpret_cast<const u16x8*>(&kh[base + r * 32 + c0]);
        *reinterpret_cast<u16x8*>(&SM[KS + r * 40 + c0]) = k8;
        u16x8 vh8 = *reinterpret_cast<const u16x8*>(&vh[base + r * 32 + c0]);
        u16x8 vl8 = *reinterpret_cast<const u16x8*>(&vl[base + r * 32 + c0]);
#pragma unroll
        for (int u = 0; u < 8; ++u) {
            const int d = c0 + u;
            SM[VTH + d * 72 + r] = vh8[u];
            SM[VTL + d * 72 + r] = vl8[u];
        }
    }
    __syncthreads();

    float bias[4][4];
#pragma unroll
    for (int reg = 0; reg < 4; ++reg)
#pragma unroll
        for (int c = 0; c < 4; ++c)
            bias[reg][c] = bias_hn[(h << 12) + ((wv * 16 + lg * 4 + reg) << 6) + c * 16 + lr];

    const int ar = wv * 16 + lr;
    bf16x8 qa = *reinterpret_cast<const bf16x8*>(&SM[QS + ar * 40 + lg * 8]);
    f32x4 S[4];
#pragma unroll
    for (int c = 0; c < 4; ++c) {
        const int br = c * 16 + lr;
        bf16x8 kb = *reinterpret_cast<const bf16x8*>(&SM[KS + br * 40 + lg * 8]);
        f32x4 s = (f32x4){0.f, 0.f, 0.f, 0.f};
        S[c] = __builtin_amdgcn_mfma_f32_16x16x32_bf16(qa, kb, s, 0, 0, 0);
    }
    // no barrier: P region is disjoint from QS/KS/VT

    const float scale = 0.1767766952966369f;  // 32^-0.5
    float p[4][4], mx[4], sm[4];
#pragma unroll
    for (int reg = 0; reg < 4; ++reg) mx[reg] = -1e30f;
#pragma unroll
    for (int reg = 0; reg < 4; ++reg)
#pragma unroll
        for (int c = 0; c < 4; ++c) {
            float s = fmaf(S[c][reg], scale, bias[reg][c]);
            p[reg][c] = s;
            mx[reg] = fmaxf(mx[reg], s);
        }
#pragma unroll
    for (int reg = 0; reg < 4; ++reg) {
        mx[reg] = fmaxf(mx[reg], __shfl_xor(mx[reg], 1));
        mx[reg] = fmaxf(mx[reg], __shfl_xor(mx[reg], 2));
        mx[reg] = fmaxf(mx[reg], __shfl_xor(mx[reg], 4));
        mx[reg] = fmaxf(mx[reg], __shfl_xor(mx[reg], 8));
        sm[reg] = 0.f;
    }
#pragma unroll
    for (int reg = 0; reg < 4; ++reg)
#pragma unroll
        for (int c = 0; c < 4; ++c) {
            float e = __expf(p[reg][c] - mx[reg]);
            p[reg][c] = e;
            sm[reg] += e;
        }
#pragma unroll
    for (int reg = 0; reg < 4; ++reg) {
        sm[reg] += __shfl_xor(sm[reg], 1);
        sm[reg] += __shfl_xor(sm[reg], 2);
        sm[reg] += __shfl_xor(sm[reg], 4);
        sm[reg] += __shfl_xor(sm[reg], 8);
        const float inv = 1.0f / sm[reg];
#pragma unroll
        for (int c = 0; c < 4; ++c) p[reg][c] *= inv;
    }

    const size_t amb = (size_t)bhid * 4096;
#pragma unroll
    for (int reg = 0; reg < 4; ++reg) {
        const int R = wv * 16 + lg * 4 + reg;
#pragma unroll
        for (int c = 0; c < 4; ++c) {
            const int C = c * 16 + lr;
            const float own = p[reg][c];
            attn_map[amb + R * 64 + C] = own;
            const float mate = __shfl_xor(own, 1);
            if (!(lr & 1)) {
                unsigned short h0 = f2bf_rn(own);
                unsigned short l0 = f2bf_rn(own - bf2f(h0));
                unsigned short h1 = f2bf_rn(mate);
                unsigned short l1 = f2bf_rn(mate - bf2f(h1));
                *reinterpret_cast<unsigned*>(&SM[PH + R * 72 + C]) =
                    (unsigned)h0 | ((unsigned)h1 << 16);
                *reinterpret_cast<unsigned*>(&SM[PL + R * 72 + C]) =
                    (unsigned)l0 | ((unsigned)l1 << 16);
            }
        }
    }
    // no barrier: wave wv's PV a-frags read rows 16wv..16wv+15 = its own writes

    f32x4 O[2];
    O[0] = (f32x4){0.f, 0.f, 0.f, 0.f};
    O[1] = (f32x4){0.f, 0.f, 0.f, 0.f};
#pragma unroll
    for (int kk = 0; kk < 2; ++kk) {
        const int pr = wv * 16 + lr;
        bf16x8 pa_h = *reinterpret_cast<const bf16x8*>(&SM[PH + pr * 72 + kk * 32 + lg * 8]);
        bf16x8 pa_l = *reinterpret_cast<const bf16x8*>(&SM[PL + pr * 72 + kk * 32 + lg * 8]);
#pragma unroll
        for (int n = 0; n < 2; ++n) {
            const int vr = n * 16 + lr;
            bf16x8 vb_h = *reinterpret_cast<const bf16x8*>(&SM[VTH + vr * 72 + kk * 32 + lg * 8]);
            bf16x8 vb_l = *reinterpret_cast<const bf16x8*>(&SM[VTL + vr * 72 + kk * 32 + lg * 8]);
            O[n] = __builtin_amdgcn_mfma_f32_16x16x32_bf16(pa_h, vb_h, O[n], 0, 0, 0);
            O[n] = __builtin_amdgcn_mfma_f32_16x16x32_bf16(pa_h, vb_l, O[n], 0, 0, 0);
            O[n] = __builtin_amdgcn_mfma_f32_16x16x32_bf16(pa_l, vb_h, O[n], 0, 0, 0);
        }
    }

    // av store: tiled layout [mb][kt=h][s][r][e], bf16 hi only
    const int mb = b >> 1;
#pragma unroll
    for (int n = 0; n < 2; ++n)
#pragma unroll
        for (int reg = 0; reg < 4; ++reg) {
            const int R  = wv * 16 + lg * 4 + reg;
            const int d  = n * 16 + lr;
            const int rl = (b & 1) * 64 + R;
            size_t off = (size_t)mb * 65536 + (size_t)h * 4096
                       + (size_t)(d >> 3) * 1024 + (size_t)rl * 8 + (d & 7);
            avh[off] = f2bf_rn(O[n][reg]);
        }
}

// ---------------------------------------------------------------------------
extern "C" void kernel_launch(void* const* d_in, const int* in_sizes, int n_in,
                              void* d_out, int out_size, void* d_ws, size_t ws_size,
                              hipStream_t stream) {
    const float* x          = (const float*)d_in[0];
    const float* qkv_w      = (const float*)d_in[1];
    const float* proj_w     = (const float*)d_in[2];
    const float* proj_b     = (const float*)d_in[3];
    const float* bias_table = (const float*)d_in[4];
    const int*   rel_index  = (const int*)d_in[5];

    float* out      = (float*)d_out;                           // [131072][512]
    float* attn_map = (float*)d_out + (size_t)M_ROWS * C_DIM;  // [B][H][64][64]

    // d_ws: Xh | Xl (tiled bf16) | qh | kh | vh | vl (bf16 planes)
    // avh aliases Xh (dead after QKV GEMM).
    const size_t PLANE = (size_t)B_WIN * H_HEADS * 64 * 32;    // 67,108,864
    unsigned short* Xh  = (unsigned short*)d_ws;
    unsigned short* Xl  = Xh + (size_t)M_ROWS * 512;
    unsigned short* qhp = Xl + (size_t)M_ROWS * 512;
    unsigned short* khp = qhp + PLANE;
    unsigned short* vhp = khp + PLANE;
    unsigned short* vlp = vhp + PLANE;
    unsigned short* avh = Xh;

    // parking: qkv_w split -> attn_map region of d_out (dead until attn
    // overwrites it); proj_w split -> qh head (dead after attn reads qh);
    // bias_hn -> out head (read by attn, before proj writes out).
    unsigned short* qwTh = (unsigned short*)attn_map;
    unsigned short* qwTl = qwTh + (size_t)1536 * 512;
    unsigned short* pwTh = qhp;
    unsigned short* pwTl = pwTh + (size_t)512 * 512;
    float* bias_hn = out;

    prep_kernel<<<33408, 256, 0, stream>>>(
        x, Xh, Xl, qkv_w, qwTh, qwTl, bias_table, rel_index, bias_hn);
    // q/k columns (0..1023): 2-pass, no Al stage
    gemm_mfma_kernel<0><<<dim3(4, 512), 512, 98304, stream>>>(
        Xh, nullptr, qwTh, qwTl, qhp, khp, nullptr, nullptr,
        nullptr, nullptr, 1536, 4, 0);
    // v columns (1024..1535): 3-pass, hi/lo output
    gemm_mfma_kernel<1><<<dim3(2, 512), 512, 131072, stream>>>(
        Xh, Xl, qwTh, qwTl, nullptr, nullptr, vhp, vlp,
        nullptr, nullptr, 1536, 2, 1024);
    attn_kernel<<<B_WIN * H_HEADS, 256, 0, stream>>>(
        qhp, khp, vhp, vlp, bias_hn, attn_map, avh);
    wsplit_kernel<<<128, 256, 0, stream>>>(proj_w, pwTh, pwTl, 512);
    gemm_mfma_kernel<2><<<dim3(2, 512), 512, 98304, stream>>>(
        avh, nullptr, pwTh, pwTl, nullptr, nullptr, nullptr, nullptr,
        proj_b, out, 512, 2, 0);
}

// Round 18
// 948.961 us; speedup vs baseline: 2.4559x; 1.0577x over previous
//
#include <hip/hip_runtime.h>
#include <cstdint>
#include <cstddef>

// Problem constants (Swin window attention)
#define B_WIN   2048
#define N_TOK   64
#define C_DIM   512
#define H_HEADS 16
#define D_HEAD  32
#define K_DIM   512
#define M_ROWS  (B_WIN * 64)   // 131072

// Tiled operand layout for GEMM operands (bf16), 128-row granules:
//   T[mb][kt][s][r][e]  mb=row>>7, kt=k>>5, s=(k>>3)&3, r=row&127, e=k&7
//   flat elem = mb*65536 + kt*4096 + s*1024 + r*8 + e

typedef __bf16 bf16x8 __attribute__((ext_vector_type(8)));
typedef float  f32x4  __attribute__((ext_vector_type(4)));
typedef unsigned short u16x8 __attribute__((ext_vector_type(8)));

__device__ __forceinline__ unsigned short f2bf_rn(float f) {
    unsigned u = __float_as_uint(f);
    u += 0x7fffu + ((u >> 16) & 1u);
    return (unsigned short)(u >> 16);
}
__device__ __forceinline__ float bf2f(unsigned short h) {
    return __uint_as_float(((unsigned)h) << 16);
}
__device__ __forceinline__ void gload16(const void* g, void* l) {
    __builtin_amdgcn_global_load_lds(
        (const __attribute__((address_space(1))) void*)g,
        (__attribute__((address_space(3))) void*)l,
        16, 0, 0);
}

// ---------------------------------------------------------------------------
// prep: fused {x -> Xh (bf16-hi, tiled) | qkv wsplit | bias_expand}
// ---------------------------------------------------------------------------
__global__ __launch_bounds__(256) void prep_kernel(
    const float* __restrict__ x,
    unsigned short* __restrict__ Xh,
    const float* __restrict__ qkv_w,
    unsigned short* __restrict__ qwTh,
    unsigned short* __restrict__ qwTl,
    const float* __restrict__ bias_table,
    const int* __restrict__ rel_index,
    float* __restrict__ bias_hn)
{
    const int blk = blockIdx.x;
    if (blk < 32768) {
        size_t e8 = ((size_t)blk * 256 + threadIdx.x) * 8;
        const int mb = (int)(e8 >> 16);
        const int w  = (int)(e8 & 65535);
        const int kt = w >> 12;
        const int s  = (w >> 10) & 3;
        const int r  = (w >> 3) & 127;
        const int m  = mb * 128 + r;
        const int k  = kt * 32 + s * 8;
        const float* src = &x[(size_t)m * 512 + k];
        float4 f0 = *reinterpret_cast<const float4*>(src);
        float4 f1 = *reinterpret_cast<const float4*>(src + 4);
        float fv[8] = {f0.x, f0.y, f0.z, f0.w, f1.x, f1.y, f1.z, f1.w};
        u16x8 hi;
#pragma unroll
        for (int j = 0; j < 8; ++j) hi[j] = f2bf_rn(fv[j]);
        *reinterpret_cast<u16x8*>(&Xh[e8]) = hi;
    } else if (blk < 33152) {
        size_t e8 = ((size_t)(blk - 32768) * 256 + threadIdx.x) * 8;
        const int mb = (int)(e8 >> 16);
        const int ww = (int)(e8 & 65535);
        const int kt = ww >> 12;
        const int s  = (ww >> 10) & 3;
        const int r  = (ww >> 3) & 127;
        const int n  = mb * 128 + r;
        const int k  = kt * 32 + s * 8;
        u16x8 hi, lo;
#pragma unroll
        for (int j = 0; j < 8; ++j) {
            float v = qkv_w[(size_t)(k + j) * 1536 + n];
            unsigned short h = f2bf_rn(v);
            hi[j] = h;
            lo[j] = f2bf_rn(v - bf2f(h));
        }
        *reinterpret_cast<u16x8*>(&qwTh[e8]) = hi;
        *reinterpret_cast<u16x8*>(&qwTl[e8]) = lo;
    } else {
        int tid = (blk - 33152) * 256 + threadIdx.x;
        int h  = tid >> 12;
        int ij = tid & 4095;
        bias_hn[tid] = bias_table[rel_index[ij] * H_HEADS + h];
    }
}

// ---------------------------------------------------------------------------
// wsplit (proj_w only; runs after attn because of its parking region)
// ---------------------------------------------------------------------------
__global__ __launch_bounds__(256) void wsplit_kernel(
    const float* __restrict__ w,
    unsigned short* __restrict__ wTh,
    unsigned short* __restrict__ wTl,
    int Ncols)
{
    size_t e8 = ((size_t)blockIdx.x * 256 + threadIdx.x) * 8;
    const int mb = (int)(e8 >> 16);
    const int ww = (int)(e8 & 65535);
    const int kt = ww >> 12;
    const int s  = (ww >> 10) & 3;
    const int r  = (ww >> 3) & 127;
    const int n  = mb * 128 + r;
    const int k  = kt * 32 + s * 8;
    u16x8 hi, lo;
#pragma unroll
    for (int j = 0; j < 8; ++j) {
        float v = w[(size_t)(k + j) * Ncols + n];
        unsigned short h = f2bf_rn(v);
        hi[j] = h;
        lo[j] = f2bf_rn(v - bf2f(h));
    }
    *reinterpret_cast<u16x8*>(&wTh[e8]) = hi;
    *reinterpret_cast<u16x8*>(&wTl[e8]) = lo;
}

// ---------------------------------------------------------------------------
// 2-pass bf16 MFMA GEMM (A exact/hi bf16, B hi/lo), 256x256 tile, BK=32,
// 16 steps, 8 waves. R13-proven 2-buffer skeleton; stages Ah,Bh,Bl (96 KiB).
//   QKV=true : epilogue routes tsel -> qh/kh/vh (pair-packed bf16);
//              tsel==2 additionally stores vl (hi/lo split of the result).
//   QKV=false: proj epilogue, fp32 + bias.
// ---------------------------------------------------------------------------
template<bool QKV>
__global__ __launch_bounds__(512, 2) void gemm_mfma_kernel(
    const unsigned short* __restrict__ ATh,
    const unsigned short* __restrict__ BTh,
    const unsigned short* __restrict__ BTl,
    unsigned short* __restrict__ qh,          // QKV
    unsigned short* __restrict__ kh,          // QKV
    unsigned short* __restrict__ vh,          // QKV
    unsigned short* __restrict__ vl,          // QKV
    const float* __restrict__ bias,           // !QKV
    float* __restrict__ out,                  // !QKV
    int Ncols_out,
    int nb_grid)                              // blocks along n (Ncols/256)
{
    extern __shared__ __align__(16) unsigned short L[];
    constexpr int AH = 0, BH = 8192, BL = 16384, STRIDE = 24576;

    const int t    = threadIdx.x;
    const int lane = t & 63;
    const int wave = t >> 6;             // 0..7
    const int lg   = lane >> 4;          // k-octet 0..3
    const int lr   = lane & 15;          // row within fragment
    const int wrow = (wave >> 2) * 128;  // 0,128
    const int wcol = (wave & 3) * 64;    // 0,64,128,192

    const int lin = blockIdx.x + gridDim.x * blockIdx.y;
    const int nwg = gridDim.x * gridDim.y;
    const int cpx = nwg >> 3;
    const int swz = (lin & 7) * cpx + (lin >> 3);
    const int m0  = (swz / nb_grid) * 256;
    const int n0  = (swz % nb_grid) * 256;
    const int mb0 = m0 >> 7;
    const int nb0 = n0 >> 7;
    const int tsel = n0 >> 9;            // block-uniform

    f32x4 acc[8][4];
#pragma unroll
    for (int i = 0; i < 8; ++i)
#pragma unroll
        for (int j = 0; j < 4; ++j) acc[i][j] = (f32x4){0.f, 0.f, 0.f, 0.f};

    auto stage = [&](int kt, int bi) {
        const int bufbase = bi * STRIDE;
#pragma unroll
        for (int i = 0; i < 2; ++i) {
            const int c = i * 512 + t;        // 0..1023
            const int r = c & 255;
            const int s = c >> 8;
            const size_t gA = (size_t)(mb0 + (r >> 7)) * 65536
                            + (size_t)kt * 4096 + s * 1024 + (r & 127) * 8;
            const size_t gB = (size_t)(nb0 + (r >> 7)) * 65536
                            + (size_t)kt * 4096 + s * 1024 + (r & 127) * 8;
            const int lo = bufbase + s * 2048 + r * 8;
            gload16(&ATh[gA], &L[lo + AH]);
            gload16(&BTh[gB], &L[lo + BH]);
            gload16(&BTl[gB], &L[lo + BL]);
        }
    };

    stage(0, 0);
    asm volatile("s_waitcnt vmcnt(0)" ::: "memory");
    __builtin_amdgcn_sched_barrier(0);
    __builtin_amdgcn_s_barrier();
    __builtin_amdgcn_sched_barrier(0);

#pragma unroll 2
    for (int ks = 0; ks < 16; ++ks) {
        const int cur = ks & 1;
        if (ks + 1 < 16) stage(ks + 1, cur ^ 1);
        const int bb = cur * STRIDE;

        bf16x8 bh[4], bl[4];
#pragma unroll
        for (int ni = 0; ni < 4; ++ni) {
            const int off = bb + lg * 2048 + (wcol + ni * 16 + lr) * 8;
            bh[ni] = *reinterpret_cast<const bf16x8*>(&L[off + BH]);
            bl[ni] = *reinterpret_cast<const bf16x8*>(&L[off + BL]);
        }
        __builtin_amdgcn_s_setprio(1);
#pragma unroll
        for (int mi = 0; mi < 8; ++mi) {
            const int aoff = bb + lg * 2048 + (wrow + mi * 16 + lr) * 8;
            bf16x8 ah = *reinterpret_cast<const bf16x8*>(&L[aoff + AH]);
#pragma unroll
            for (int ni = 0; ni < 4; ++ni)
                acc[mi][ni] = __builtin_amdgcn_mfma_f32_16x16x32_bf16(ah, bh[ni], acc[mi][ni], 0, 0, 0);
#pragma unroll
            for (int ni = 0; ni < 4; ++ni)
                acc[mi][ni] = __builtin_amdgcn_mfma_f32_16x16x32_bf16(ah, bl[ni], acc[mi][ni], 0, 0, 0);
        }
        __builtin_amdgcn_s_setprio(0);

        asm volatile("s_waitcnt vmcnt(0)" ::: "memory");
        __builtin_amdgcn_sched_barrier(0);
        __builtin_amdgcn_s_barrier();
        __builtin_amdgcn_sched_barrier(0);
    }

    // C/D layout: col = lane&15, row = (lane>>4)*4 + reg   [m89-verified]
    if constexpr (QKV) {
        unsigned short* dh = (tsel == 0) ? qh : (tsel == 1) ? kh : vh;
#pragma unroll
        for (int mi = 0; mi < 8; ++mi)
#pragma unroll
            for (int ni = 0; ni < 4; ++ni) {
                const int col = n0 + wcol + ni * 16 + lr;
                const int h   = (col >> 5) & 15;
                const int dd  = col & 31;
#pragma unroll
                for (int reg = 0; reg < 4; ++reg) {
                    const int row = m0 + wrow + mi * 16 + lg * 4 + reg;
                    const int b = row >> 6, n = row & 63;
                    const size_t idx = ((((size_t)b * H_HEADS + h) * 64) + n) * 32 + dd;
                    const float own  = acc[mi][ni][reg];
                    const float mate = __shfl_xor(own, 1);
                    if (!(lr & 1)) {
                        unsigned short h0 = f2bf_rn(own);
                        unsigned short h1 = f2bf_rn(mate);
                        *reinterpret_cast<unsigned*>(&dh[idx]) =
                            (unsigned)h0 | ((unsigned)h1 << 16);
                        if (tsel == 2) {
                            unsigned short l0 = f2bf_rn(own  - bf2f(h0));
                            unsigned short l1 = f2bf_rn(mate - bf2f(h1));
                            *reinterpret_cast<unsigned*>(&vl[idx]) =
                                (unsigned)l0 | ((unsigned)l1 << 16);
                        }
                    }
                }
            }
    } else {
#pragma unroll
        for (int mi = 0; mi < 8; ++mi)
#pragma unroll
            for (int ni = 0; ni < 4; ++ni) {
                const int col = n0 + wcol + ni * 16 + lr;
                const float pb = bias[col];
#pragma unroll
                for (int reg = 0; reg < 4; ++reg) {
                    const int row = m0 + wrow + mi * 16 + lg * 4 + reg;
                    out[(size_t)row * Ncols_out + col] = acc[mi][ni][reg] + pb;
                }
            }
    }
}

// ---------------------------------------------------------------------------
// MFMA window attention (unchanged from R15/R17 — proven). q,k bf16 (1-pass
// QK^T); v hi/lo (3-pass PV); av emitted bf16-hi (tiled).
// ---------------------------------------------------------------------------
__global__ __launch_bounds__(256, 4) void attn_kernel(
    const unsigned short* __restrict__ qh,   // [B][H][64][32] bf16
    const unsigned short* __restrict__ kh,
    const unsigned short* __restrict__ vh,
    const unsigned short* __restrict__ vl,
    const float* __restrict__ bias_hn,       // [H][64][64]
    float* __restrict__ attn_map,            // [B][H][64][64]
    unsigned short* __restrict__ avh)        // tiled bf16 hi
{
    __shared__ __align__(16) unsigned short SM[18944];
    constexpr int VTH = 0, VTL = 2304;       // [32 d][72 r]
    constexpr int QS  = 4608, KS = 7168;     // [64][40]
    constexpr int PH  = 9728, PL = 14336;    // [64][72]

    const int bhid = blockIdx.x;
    const int b    = bhid >> 4;
    const int h    = bhid & 15;
    const int t    = threadIdx.x;
    const int lane = t & 63;
    const int wv   = t >> 6;
    const int lg   = lane >> 4;
    const int lr   = lane & 15;

    const size_t base = (size_t)bhid * 2048;   // 64*32 per (b,h)

    {
        const int r  = t >> 2;
        const int c0 = (t & 3) * 8;
        u16x8 q8 = *reinterpret_cast<const u16x8*>(&qh[base + r * 32 + c0]);
        *reinterpret_cast<u16x8*>(&SM[QS + r * 40 + c0]) = q8;
        u16x8 k8 = *reinterpret_cast<const u16x8*>(&kh[base + r * 32 + c0]);
        *reinterpret_cast<u16x8*>(&SM[KS + r * 40 + c0]) = k8;
        u16x8 vh8 = *reinterpret_cast<const u16x8*>(&vh[base + r * 32 + c0]);
        u16x8 vl8 = *reinterpret_cast<const u16x8*>(&vl[base + r * 32 + c0]);
#pragma unroll
        for (int u = 0; u < 8; ++u) {
            const int d = c0 + u;
            SM[VTH + d * 72 + r] = vh8[u];
            SM[VTL + d * 72 + r] = vl8[u];
        }
    }
    __syncthreads();

    float bias[4][4];
#pragma unroll
    for (int reg = 0; reg < 4; ++reg)
#pragma unroll
        for (int c = 0; c < 4; ++c)
            bias[reg][c] = bias_hn[(h << 12) + ((wv * 16 + lg * 4 + reg) << 6) + c * 16 + lr];

    const int ar = wv * 16 + lr;
    bf16x8 qa = *reinterpret_cast<const bf16x8*>(&SM[QS + ar * 40 + lg * 8]);
    f32x4 S[4];
#pragma unroll
    for (int c = 0; c < 4; ++c) {
        const int br = c * 16 + lr;
        bf16x8 kb = *reinterpret_cast<const bf16x8*>(&SM[KS + br * 40 + lg * 8]);
        f32x4 s = (f32x4){0.f, 0.f, 0.f, 0.f};
        S[c] = __builtin_amdgcn_mfma_f32_16x16x32_bf16(qa, kb, s, 0, 0, 0);
    }
    // no barrier: P region is disjoint from QS/KS/VT

    const float scale = 0.1767766952966369f;  // 32^-0.5
    float p[4][4], mx[4], sm[4];
#pragma unroll
    for (int reg = 0; reg < 4; ++reg) mx[reg] = -1e30f;
#pragma unroll
    for (int reg = 0; reg < 4; ++reg)
#pragma unroll
        for (int c = 0; c < 4; ++c) {
            float s = fmaf(S[c][reg], scale, bias[reg][c]);
            p[reg][c] = s;
            mx[reg] = fmaxf(mx[reg], s);
        }
#pragma unroll
    for (int reg = 0; reg < 4; ++reg) {
        mx[reg] = fmaxf(mx[reg], __shfl_xor(mx[reg], 1));
        mx[reg] = fmaxf(mx[reg], __shfl_xor(mx[reg], 2));
        mx[reg] = fmaxf(mx[reg], __shfl_xor(mx[reg], 4));
        mx[reg] = fmaxf(mx[reg], __shfl_xor(mx[reg], 8));
        sm[reg] = 0.f;
    }
#pragma unroll
    for (int reg = 0; reg < 4; ++reg)
#pragma unroll
        for (int c = 0; c < 4; ++c) {
            float e = __expf(p[reg][c] - mx[reg]);
            p[reg][c] = e;
            sm[reg] += e;
        }
#pragma unroll
    for (int reg = 0; reg < 4; ++reg) {
        sm[reg] += __shfl_xor(sm[reg], 1);
        sm[reg] += __shfl_xor(sm[reg], 2);
        sm[reg] += __shfl_xor(sm[reg], 4);
        sm[reg] += __shfl_xor(sm[reg], 8);
        const float inv = 1.0f / sm[reg];
#pragma unroll
        for (int c = 0; c < 4; ++c) p[reg][c] *= inv;
    }

    const size_t amb = (size_t)bhid * 4096;
#pragma unroll
    for (int reg = 0; reg < 4; ++reg) {
        const int R = wv * 16 + lg * 4 + reg;
#pragma unroll
        for (int c = 0; c < 4; ++c) {
            const int C = c * 16 + lr;
            const float own = p[reg][c];
            attn_map[amb + R * 64 + C] = own;
            const float mate = __shfl_xor(own, 1);
            if (!(lr & 1)) {
                unsigned short h0 = f2bf_rn(own);
                unsigned short l0 = f2bf_rn(own - bf2f(h0));
                unsigned short h1 = f2bf_rn(mate);
                unsigned short l1 = f2bf_rn(mate - bf2f(h1));
                *reinterpret_cast<unsigned*>(&SM[PH + R * 72 + C]) =
                    (unsigned)h0 | ((unsigned)h1 << 16);
                *reinterpret_cast<unsigned*>(&SM[PL + R * 72 + C]) =
                    (unsigned)l0 | ((unsigned)l1 << 16);
            }
        }
    }
    // no barrier: wave wv's PV a-frags read rows 16wv..16wv+15 = its own writes

    f32x4 O[2];
    O[0] = (f32x4){0.f, 0.f, 0.f, 0.f};
    O[1] = (f32x4){0.f, 0.f, 0.f, 0.f};
#pragma unroll
    for (int kk = 0; kk < 2; ++kk) {
        const int pr = wv * 16 + lr;
        bf16x8 pa_h = *reinterpret_cast<const bf16x8*>(&SM[PH + pr * 72 + kk * 32 + lg * 8]);
        bf16x8 pa_l = *reinterpret_cast<const bf16x8*>(&SM[PL + pr * 72 + kk * 32 + lg * 8]);
#pragma unroll
        for (int n = 0; n < 2; ++n) {
            const int vr = n * 16 + lr;
            bf16x8 vb_h = *reinterpret_cast<const bf16x8*>(&SM[VTH + vr * 72 + kk * 32 + lg * 8]);
            bf16x8 vb_l = *reinterpret_cast<const bf16x8*>(&SM[VTL + vr * 72 + kk * 32 + lg * 8]);
            O[n] = __builtin_amdgcn_mfma_f32_16x16x32_bf16(pa_h, vb_h, O[n], 0, 0, 0);
            O[n] = __builtin_amdgcn_mfma_f32_16x16x32_bf16(pa_h, vb_l, O[n], 0, 0, 0);
            O[n] = __builtin_amdgcn_mfma_f32_16x16x32_bf16(pa_l, vb_h, O[n], 0, 0, 0);
        }
    }

    // av store: tiled layout [mb][kt=h][s][r][e], bf16 hi only
    const int mb = b >> 1;
#pragma unroll
    for (int n = 0; n < 2; ++n)
#pragma unroll
        for (int reg = 0; reg < 4; ++reg) {
            const int R  = wv * 16 + lg * 4 + reg;
            const int d  = n * 16 + lr;
            const int rl = (b & 1) * 64 + R;
            size_t off = (size_t)mb * 65536 + (size_t)h * 4096
                       + (size_t)(d >> 3) * 1024 + (size_t)rl * 8 + (d & 7);
            avh[off] = f2bf_rn(O[n][reg]);
        }
}

// ---------------------------------------------------------------------------
extern "C" void kernel_launch(void* const* d_in, const int* in_sizes, int n_in,
                              void* d_out, int out_size, void* d_ws, size_t ws_size,
                              hipStream_t stream) {
    const float* x          = (const float*)d_in[0];
    const float* qkv_w      = (const float*)d_in[1];
    const float* proj_w     = (const float*)d_in[2];
    const float* proj_b     = (const float*)d_in[3];
    const float* bias_table = (const float*)d_in[4];
    const int*   rel_index  = (const int*)d_in[5];

    float* out      = (float*)d_out;                           // [131072][512]
    float* attn_map = (float*)d_out + (size_t)M_ROWS * C_DIM;  // [B][H][64][64]

    // d_ws: Xh (tiled bf16) | qh | kh | vh | vl (bf16 planes)  (~671 MB)
    // avh aliases Xh (dead after QKV GEMM).
    const size_t PLANE = (size_t)B_WIN * H_HEADS * 64 * 32;    // 67,108,864
    unsigned short* Xh  = (unsigned short*)d_ws;
    unsigned short* qhp = Xh + (size_t)M_ROWS * 512;
    unsigned short* khp = qhp + PLANE;
    unsigned short* vhp = khp + PLANE;
    unsigned short* vlp = vhp + PLANE;
    unsigned short* avh = Xh;

    // parking: qkv_w split -> attn_map region of d_out (dead until attn
    // overwrites it); proj_w split -> qh head (dead after attn reads qh);
    // bias_hn -> out head (read by attn, before proj writes out).
    unsigned short* qwTh = (unsigned short*)attn_map;
    unsigned short* qwTl = qwTh + (size_t)1536 * 512;
    unsigned short* pwTh = qhp;
    unsigned short* pwTl = pwTh + (size_t)512 * 512;
    float* bias_hn = out;

    prep_kernel<<<33408, 256, 0, stream>>>(
        x, Xh, qkv_w, qwTh, qwTl, bias_table, rel_index, bias_hn);
    gemm_mfma_kernel<true><<<dim3(6, 512), 512, 98304, stream>>>(
        Xh, qwTh, qwTl, qhp, khp, vhp, vlp, nullptr, nullptr, 1536, 6);
    attn_kernel<<<B_WIN * H_HEADS, 256, 0, stream>>>(
        qhp, khp, vhp, vlp, bias_hn, attn_map, avh);
    wsplit_kernel<<<128, 256, 0, stream>>>(proj_w, pwTh, pwTl, 512);
    gemm_mfma_kernel<false><<<dim3(2, 512), 512, 98304, stream>>>(
        avh, pwTh, pwTl, nullptr, nullptr, nullptr, nullptr,
        proj_b, out, 512, 2);
}